// Round 8
// baseline (84.685 us; speedup 1.0000x reference)
//
#include <hip/hip_runtime.h>
#include <hip/hip_bf16.h>
#include <cstdint>
#include <cstddef>

// Problem constants (B=4, H=16, S=4096, E=128)
#define S_LEN 4096
#define E_DIM 128
#define NROWS (4 * 16 * 4096)   // 262144 token rows
#define TOK_TILE 64             // tokens per LDS tile (32 KB f32)
#define GRID_MAIN 512
#define T_TILES (NROWS / TOK_TILE / GRID_MAIN)   // 8

typedef __attribute__((ext_vector_type(8))) short bh8;   // 8 bf16 (4 VGPRs) MFMA frag
typedef __attribute__((ext_vector_type(4))) float f4;    // MFMA accumulator
typedef unsigned short u16;

__device__ __forceinline__ u16 f2bf(float f) {
    union { float f; uint32_t u; } v; v.f = f;
    uint32_t r = v.u + 0x7FFFu + ((v.u >> 16) & 1u);   // round-to-nearest-even
    return (u16)(r >> 16);
}
__device__ __forceinline__ short bfc(float f) {
    __hip_bfloat16 h = __float2bfloat16(f);
    return *reinterpret_cast<short*>(&h);
}
__device__ __forceinline__ float bf2f(u16 u) {
    union { uint32_t u; float f; } v; v.u = ((uint32_t)u) << 16;
    return v.f;
}

// ============================================================================
// Fused prologue: block 0 = Cayley chain via MFMA (1 CU, ~3 µs);
// blocks 1..16 = interleaved cos/sin table csT[s*128+2f]={cos,sin}.
// Antisymmetry: A^T=-A, A2/A4 symmetric => both MFMA operands read as ROWS.
//   A2 = -RR(A,A); A4 = RR(A2,A2); Y1 = A+A2
//   Q  = P - I = 2*(RR(A2,Y1) + RR(A4,Y1) + A2 - A)   (err O(|A|^7))
// ============================================================================
__device__ __forceinline__ bh8 ldsRow(const u16* M, int row, int c) {
    return *(const bh8*)(&M[row * 128 + ((c ^ (row & 15)) * 8)]);
}
__device__ __forceinline__ int swzIdx(int n, int m) {
    return n * 128 + (((m >> 3) ^ (n & 15)) * 8) + (m & 7);
}

__global__ __launch_bounds__(1024) void k_pro(const float* __restrict__ Sc,
        const float* __restrict__ pos, u16* __restrict__ Qb,
        float* __restrict__ csT) {
    if (blockIdx.x != 0) {
        int t = (blockIdx.x - 1) * 1024 + threadIdx.x;
        for (int e = t; e < S_LEN * 64; e += 16 * 1024) {
            int s = e >> 6, f = e & 63;
            float freq = exp2f(-0.20762050593046015f * (float)f);  // 10000^(-f/64)
            float sv, cv;
            sincosf(pos[s] * freq, &sv, &cv);
            csT[s * 128 + 2 * f]     = cv;
            csT[s * 128 + 2 * f + 1] = sv;
        }
        return;
    }
    __shared__ u16 Abf[128 * 128];
    __shared__ u16 A2bf[128 * 128];
    __shared__ u16 Y1bf[128 * 128];
    __shared__ u16 A4bf[128 * 128];

    for (int e = threadIdx.x; e < 16384; e += 1024) {
        int i = e >> 7, j = e & 127;
        float a = 0.5f * (Sc[i * 128 + j] - Sc[j * 128 + i]);
        Abf[swzIdx(i, j)] = f2bf(a);
    }
    __syncthreads();

    const int wave = threadIdx.x >> 6;      // 16 waves
    const int lane = threadIdx.x & 63;
    const int lhi = lane >> 4, llo = lane & 15;
    const int sm = wave & 7;                // m-strip (16 cols)
    const int nh = wave >> 3;               // n half (4 n-tiles)

    // ---- pass 1: acc = RR(A,A); A2 = -acc; Y1 = A + A2 ----
    {
        f4 acc[4];
        #pragma unroll
        for (int t = 0; t < 4; ++t) { f4 z = {0.f,0.f,0.f,0.f}; acc[t] = z; }
        #pragma unroll
        for (int kk = 0; kk < 4; ++kk) {
            bh8 yf = ldsRow(Abf, sm * 16 + llo, kk * 4 + lhi);
            #pragma unroll
            for (int t = 0; t < 4; ++t) {
                bh8 xf = ldsRow(Abf, (nh * 4 + t) * 16 + llo, kk * 4 + lhi);
                acc[t] = __builtin_amdgcn_mfma_f32_16x16x32_bf16(xf, yf, acc[t], 0, 0, 0);
            }
        }
        __syncthreads();
        #pragma unroll
        for (int t = 0; t < 4; ++t) {
            #pragma unroll
            for (int r = 0; r < 4; ++r) {
                int n = (nh * 4 + t) * 16 + lhi * 4 + r, m = sm * 16 + llo;
                float a2 = -acc[t][r];
                A2bf[swzIdx(n, m)] = f2bf(a2);
                Y1bf[swzIdx(n, m)] = f2bf(a2 + bf2f(Abf[swzIdx(n, m)]));
            }
        }
    }
    __syncthreads();
    // ---- pass 2: A4 = RR(A2,A2) ----
    {
        f4 acc[4];
        #pragma unroll
        for (int t = 0; t < 4; ++t) { f4 z = {0.f,0.f,0.f,0.f}; acc[t] = z; }
        #pragma unroll
        for (int kk = 0; kk < 4; ++kk) {
            bh8 yf = ldsRow(A2bf, sm * 16 + llo, kk * 4 + lhi);
            #pragma unroll
            for (int t = 0; t < 4; ++t) {
                bh8 xf = ldsRow(A2bf, (nh * 4 + t) * 16 + llo, kk * 4 + lhi);
                acc[t] = __builtin_amdgcn_mfma_f32_16x16x32_bf16(xf, yf, acc[t], 0, 0, 0);
            }
        }
        #pragma unroll
        for (int t = 0; t < 4; ++t)
            #pragma unroll
            for (int r = 0; r < 4; ++r) {
                int n = (nh * 4 + t) * 16 + lhi * 4 + r, m = sm * 16 + llo;
                A4bf[swzIdx(n, m)] = f2bf(acc[t][r]);
            }
    }
    __syncthreads();
    // ---- pass 3: acc = RR(A2,Y1) + RR(A4,Y1); Q = 2*(acc + A2 - A) ----
    {
        f4 acc[4];
        #pragma unroll
        for (int t = 0; t < 4; ++t) { f4 z = {0.f,0.f,0.f,0.f}; acc[t] = z; }
        #pragma unroll
        for (int kk = 0; kk < 4; ++kk) {
            bh8 yf = ldsRow(Y1bf, sm * 16 + llo, kk * 4 + lhi);
            #pragma unroll
            for (int t = 0; t < 4; ++t) {
                bh8 xf = ldsRow(A2bf, (nh * 4 + t) * 16 + llo, kk * 4 + lhi);
                acc[t] = __builtin_amdgcn_mfma_f32_16x16x32_bf16(xf, yf, acc[t], 0, 0, 0);
            }
        }
        #pragma unroll
        for (int kk = 0; kk < 4; ++kk) {
            bh8 yf = ldsRow(Y1bf, sm * 16 + llo, kk * 4 + lhi);
            #pragma unroll
            for (int t = 0; t < 4; ++t) {
                bh8 xf = ldsRow(A4bf, (nh * 4 + t) * 16 + llo, kk * 4 + lhi);
                acc[t] = __builtin_amdgcn_mfma_f32_16x16x32_bf16(xf, yf, acc[t], 0, 0, 0);
            }
        }
        #pragma unroll
        for (int t = 0; t < 4; ++t)
            #pragma unroll
            for (int r = 0; r < 4; ++r) {
                int n = (nh * 4 + t) * 16 + lhi * 4 + r, m = sm * 16 + llo;
                float q = 2.0f * (acc[t][r] + bf2f(A2bf[swzIdx(n, m)])
                                            - bf2f(Abf[swzIdx(n, m)]));
                Qb[n * 128 + m] = f2bf(q);
            }
    }
}

// ---------- async stage of one 64-token tile (32 KB) into LDS ----------
// LDS linear in 16B-chunk index; global source pre-swizzled (rule #21):
// LDS[tok][pc] holds global chunk c = pc ^ (tok & 7).
__device__ __forceinline__ void stage_tile(const float* gbase, float* ldsbase,
                                           int wave, int lane) {
    #pragma unroll
    for (int i = 0; i < 8; ++i) {
        const int L = (i * 4 + wave) * 64 + lane;        // chunk index 0..2047
        const int tok = L >> 5, pc = L & 31;
        const int c = pc ^ (tok & 7);
        const float* gp = gbase + tok * E_DIM + c * 4;
        float* lp = ldsbase + (size_t)(i * 4 + wave) * 256;   // wave-uniform base
        __builtin_amdgcn_global_load_lds(
            (const __attribute__((address_space(1))) void*)gp,
            (__attribute__((address_space(3))) void*)lp, 16, 0, 0);
    }
}

// ============================================================================
// Main fused kernel: out = RoPE(x + x*Q^T)
// Q in PINNED REGISTERS (32 bh8 = 128 VGPR, loaded once — asm pin stops remat).
// LDS = x double buffer only (64 KB) -> 2 blocks/CU, 8 waves/CU (2/SIMD TLP).
// Counted-vmcnt pipeline (T4): per iter VMEM order
//   [A] 8 csT loads  [B] 8 global_load_lds (stage t+1)  [C] 8 f4 stores
// End-of-iter s_waitcnt vmcnt(8): stage complete, stores still in flight.
// ============================================================================
__global__ __launch_bounds__(256, 2) void k_main(const float* __restrict__ x,
        const u16* __restrict__ Qb, const float* __restrict__ csT,
        float* __restrict__ out) {
    __shared__ float xb[2][TOK_TILE * E_DIM];  // 2 x 32 KB x tiles

    const int wave = threadIdx.x >> 6;
    const int lane = threadIdx.x & 63;
    const int lhi = lane >> 4, llo = lane & 15;
    const int wtok = wave * 16 + llo;        // this lane's token within tile
    const int sw = wtok & 7;                 // x-swizzle key
    const int tile0 = blockIdx.x * T_TILES;

    // Q fragments into registers: qf[t*4+kk] = Q[n=t*16+llo][k=kk*32+lhi*8 .. +7]
    bh8 qf[32];
    #pragma unroll
    for (int t = 0; t < 8; ++t)
        #pragma unroll
        for (int kk = 0; kk < 4; ++kk)
            qf[t * 4 + kk] = *(const bh8*)(Qb + (size_t)(t * 16 + llo) * E_DIM
                                              + kk * 32 + lhi * 8);
    #pragma unroll
    for (int i = 0; i < 32; ++i) asm volatile("" : "+v"(qf[i]));   // pin: no remat

    stage_tile(x + (size_t)tile0 * TOK_TILE * E_DIM, &xb[0][0], wave, lane);
    __syncthreads();                          // one-time full drain (vmcnt 0)

    for (int tl = 0; tl < T_TILES; ++tl) {
        const int cur = tl & 1;
        const int m = (tile0 + tl) * TOK_TILE + wtok;
        const int s = m & (S_LEN - 1);

        // [A] csT loads -> regs (issued first; waits never drain [B])
        f4 cs[8];
        const float* csp = csT + (size_t)s * 128;
        #pragma unroll
        for (int t = 0; t < 4; ++t) {
            cs[t]     = *(const f4*)(csp + t * 16 + lhi * 4);
            cs[4 + t] = *(const f4*)(csp + 64 + t * 16 + lhi * 4);
        }
        __builtin_amdgcn_sched_barrier(0);

        // [B] stage next tile into the other buffer
        if (tl + 1 < T_TILES)
            stage_tile(x + (size_t)(tile0 + tl + 1) * TOK_TILE * E_DIM,
                       &xb[cur ^ 1][0], wave, lane);
        __builtin_amdgcn_sched_barrier(0);

        // compute tile t from xb[cur]
        const float* xcur = &xb[cur][0] + wtok * E_DIM;

        bh8 frag[4];
        #pragma unroll
        for (int kk = 0; kk < 4; ++kk) {
            const int c0 = kk * 8 + lhi * 2;
            f4 v0 = *(const f4*)(xcur + ((c0)     ^ sw) * 4);
            f4 v1 = *(const f4*)(xcur + ((c0 + 1) ^ sw) * 4);
            bh8 a;
            #pragma unroll
            for (int j = 0; j < 4; ++j) { a[j] = bfc(v0[j]); a[4 + j] = bfc(v1[j]); }
            frag[kk] = a;
        }

        f4 acc[8];
        #pragma unroll
        for (int t = 0; t < 8; ++t) { f4 z = {0.f, 0.f, 0.f, 0.f}; acc[t] = z; }
        #pragma unroll
        for (int kk = 0; kk < 4; ++kk) {
            #pragma unroll
            for (int t = 0; t < 8; ++t) {
                acc[t] = __builtin_amdgcn_mfma_f32_16x16x32_bf16(
                             qf[t * 4 + kk], frag[kk], acc[t], 0, 0, 0);
            }
        }

        // epilogue + [C] stores (8 f4, youngest VMEM ops of the iter)
        float* orow = out + (size_t)m * E_DIM;
        #pragma unroll
        for (int t = 0; t < 4; ++t) {
            const int n0 = t * 16 + lhi * 4;
            const int cl = t * 4 + lhi;              // 16B chunk of cols n0..n0+3
            f4 xlo = *(const f4*)(xcur + (cl ^ sw) * 4);
            f4 xhi = *(const f4*)(xcur + ((16 + cl) ^ sw) * 4);
            f4 olo, ohi;
            #pragma unroll
            for (int r = 0; r < 4; ++r) {
                float xt1 = acc[t][r] + xlo[r];
                float xt2 = acc[t + 4][r] + xhi[r];
                float c1 = cs[t][(r >> 1) * 2],     s1 = cs[t][(r >> 1) * 2 + 1];
                float c2 = cs[4 + t][(r >> 1) * 2], s2 = cs[4 + t][(r >> 1) * 2 + 1];
                olo[r] = xt1 * c1 - xt2 * s1;
                ohi[r] = xt2 * c2 + xt1 * s2;
            }
            *(f4*)(orow + n0) = olo;
            *(f4*)(orow + n0 + 64) = ohi;
        }

        // end of iter: stage(t+1) done, only the 8 stores may remain in flight
        __builtin_amdgcn_sched_barrier(0);
        asm volatile("s_waitcnt vmcnt(8)" ::: "memory");
        __builtin_amdgcn_sched_barrier(0);
        __builtin_amdgcn_s_barrier();
        __builtin_amdgcn_sched_barrier(0);
    }
}

extern "C" void kernel_launch(void* const* d_in, const int* in_sizes, int n_in,
                              void* d_out, int out_size, void* d_ws, size_t ws_size,
                              hipStream_t stream) {
    const float* x   = (const float*)d_in[0];
    const float* pos = (const float*)d_in[1];
    const float* Sc  = (const float*)d_in[2];
    float* out = (float*)d_out;

    char* ws = (char*)d_ws;
    u16* Qb     = (u16*)(ws);              // 32 KB bf16 Q = P - I
    float* csT  = (float*)(ws + 32768);    // 2 MB interleaved cos/sin

    k_pro<<<17, 1024, 0, stream>>>(Sc, pos, Qb, csT);
    k_main<<<GRID_MAIN, 256, 0, stream>>>(x, Qb, csT, out);
}

// Round 9
// 71.449 us; speedup vs baseline: 1.1852x; 1.1852x over previous
//
#include <hip/hip_runtime.h>
#include <hip/hip_bf16.h>
#include <cstdint>
#include <cstddef>

// Problem constants (B=4, H=16, S=4096, E=128)
#define S_LEN 4096
#define E_DIM 128
#define NROWS (4 * 16 * 4096)   // 262144 token rows
#define GRID_MAIN 512
#define ITERS 8                 // wave-iters; 512 blk x 4 waves x 16 tok x 8 = NROWS

typedef __attribute__((ext_vector_type(8))) short bh8;   // 8 bf16 MFMA frag
typedef __attribute__((ext_vector_type(4))) float f4;
typedef unsigned short u16;

__device__ __forceinline__ u16 f2bf(float f) {
    union { float f; uint32_t u; } v; v.f = f;
    uint32_t r = v.u + 0x7FFFu + ((v.u >> 16) & 1u);
    return (u16)(r >> 16);
}
__device__ __forceinline__ short bfc(float f) {
    __hip_bfloat16 h = __float2bfloat16(f);
    return *reinterpret_cast<short*>(&h);
}
__device__ __forceinline__ float bf2f(u16 u) {
    union { uint32_t u; float f; } v; v.u = ((uint32_t)u) << 16;
    return v.f;
}

// ============================================================================
// Fused prologue (unchanged from R7 — verified): block 0 = Cayley chain via
// MFMA; blocks 1..16 = interleaved cos/sin table csT[s*128+2f]={cos,sin}.
// ============================================================================
__device__ __forceinline__ bh8 ldsRow(const u16* M, int row, int c) {
    return *(const bh8*)(&M[row * 128 + ((c ^ (row & 15)) * 8)]);
}
__device__ __forceinline__ int swzIdx(int n, int m) {
    return n * 128 + (((m >> 3) ^ (n & 15)) * 8) + (m & 7);
}

__global__ __launch_bounds__(1024) void k_pro(const float* __restrict__ Sc,
        const float* __restrict__ pos, u16* __restrict__ Qb,
        float* __restrict__ csT) {
    if (blockIdx.x != 0) {
        int t = (blockIdx.x - 1) * 1024 + threadIdx.x;
        for (int e = t; e < S_LEN * 64; e += 16 * 1024) {
            int s = e >> 6, f = e & 63;
            float freq = exp2f(-0.20762050593046015f * (float)f);  // 10000^(-f/64)
            float sv, cv;
            sincosf(pos[s] * freq, &sv, &cv);
            csT[s * 128 + 2 * f]     = cv;
            csT[s * 128 + 2 * f + 1] = sv;
        }
        return;
    }
    __shared__ u16 Abf[128 * 128];
    __shared__ u16 A2bf[128 * 128];
    __shared__ u16 Y1bf[128 * 128];
    __shared__ u16 A4bf[128 * 128];

    for (int e = threadIdx.x; e < 16384; e += 1024) {
        int i = e >> 7, j = e & 127;
        float a = 0.5f * (Sc[i * 128 + j] - Sc[j * 128 + i]);
        Abf[swzIdx(i, j)] = f2bf(a);
    }
    __syncthreads();

    const int wave = threadIdx.x >> 6;
    const int lane = threadIdx.x & 63;
    const int lhi = lane >> 4, llo = lane & 15;
    const int sm = wave & 7;
    const int nh = wave >> 3;

    {   // pass 1: A2 = -RR(A,A); Y1 = A + A2
        f4 acc[4];
        #pragma unroll
        for (int t = 0; t < 4; ++t) { f4 z = {0.f,0.f,0.f,0.f}; acc[t] = z; }
        #pragma unroll
        for (int kk = 0; kk < 4; ++kk) {
            bh8 yf = ldsRow(Abf, sm * 16 + llo, kk * 4 + lhi);
            #pragma unroll
            for (int t = 0; t < 4; ++t) {
                bh8 xf = ldsRow(Abf, (nh * 4 + t) * 16 + llo, kk * 4 + lhi);
                acc[t] = __builtin_amdgcn_mfma_f32_16x16x32_bf16(xf, yf, acc[t], 0, 0, 0);
            }
        }
        __syncthreads();
        #pragma unroll
        for (int t = 0; t < 4; ++t)
            #pragma unroll
            for (int r = 0; r < 4; ++r) {
                int n = (nh * 4 + t) * 16 + lhi * 4 + r, m = sm * 16 + llo;
                float a2 = -acc[t][r];
                A2bf[swzIdx(n, m)] = f2bf(a2);
                Y1bf[swzIdx(n, m)] = f2bf(a2 + bf2f(Abf[swzIdx(n, m)]));
            }
    }
    __syncthreads();
    {   // pass 2: A4 = RR(A2,A2)
        f4 acc[4];
        #pragma unroll
        for (int t = 0; t < 4; ++t) { f4 z = {0.f,0.f,0.f,0.f}; acc[t] = z; }
        #pragma unroll
        for (int kk = 0; kk < 4; ++kk) {
            bh8 yf = ldsRow(A2bf, sm * 16 + llo, kk * 4 + lhi);
            #pragma unroll
            for (int t = 0; t < 4; ++t) {
                bh8 xf = ldsRow(A2bf, (nh * 4 + t) * 16 + llo, kk * 4 + lhi);
                acc[t] = __builtin_amdgcn_mfma_f32_16x16x32_bf16(xf, yf, acc[t], 0, 0, 0);
            }
        }
        #pragma unroll
        for (int t = 0; t < 4; ++t)
            #pragma unroll
            for (int r = 0; r < 4; ++r) {
                int n = (nh * 4 + t) * 16 + lhi * 4 + r, m = sm * 16 + llo;
                A4bf[swzIdx(n, m)] = f2bf(acc[t][r]);
            }
    }
    __syncthreads();
    {   // pass 3: Q = 2*(RR(A2,Y1) + RR(A4,Y1) + A2 - A)
        f4 acc[4];
        #pragma unroll
        for (int t = 0; t < 4; ++t) { f4 z = {0.f,0.f,0.f,0.f}; acc[t] = z; }
        #pragma unroll
        for (int kk = 0; kk < 4; ++kk) {
            bh8 yf = ldsRow(Y1bf, sm * 16 + llo, kk * 4 + lhi);
            #pragma unroll
            for (int t = 0; t < 4; ++t) {
                bh8 xf = ldsRow(A2bf, (nh * 4 + t) * 16 + llo, kk * 4 + lhi);
                acc[t] = __builtin_amdgcn_mfma_f32_16x16x32_bf16(xf, yf, acc[t], 0, 0, 0);
            }
        }
        #pragma unroll
        for (int kk = 0; kk < 4; ++kk) {
            bh8 yf = ldsRow(Y1bf, sm * 16 + llo, kk * 4 + lhi);
            #pragma unroll
            for (int t = 0; t < 4; ++t) {
                bh8 xf = ldsRow(A4bf, (nh * 4 + t) * 16 + llo, kk * 4 + lhi);
                acc[t] = __builtin_amdgcn_mfma_f32_16x16x32_bf16(xf, yf, acc[t], 0, 0, 0);
            }
        }
        #pragma unroll
        for (int t = 0; t < 4; ++t)
            #pragma unroll
            for (int r = 0; r < 4; ++r) {
                int n = (nh * 4 + t) * 16 + lhi * 4 + r, m = sm * 16 + llo;
                float q = 2.0f * (acc[t][r] + bf2f(A2bf[swzIdx(n, m)])
                                            - bf2f(Abf[swzIdx(n, m)]));
                Qb[n * 128 + m] = f2bf(q);
            }
    }
}

// ============================================================================
// Main kernel: copy-shaped streaming. Every global access is 1 KB contiguous
// per wave instruction. No barriers in the loop; waves free-run (8/CU).
// Per wave-iter (16 tokens):
//   load x store-layout -> LDS transpose -> bf16 frags -> 32 MFMA (Q in LDS)
//   -> acc transposed back -> + x -> RoPE in store-layout (partner via shfl)
//   -> contiguous stores.
// Per-wave 8 KB scratch, XOR swizzle a=tok*32+(ch^tok): all 4 ds phases are
// bank-uniform (verified analytically).
// ============================================================================
__global__ __launch_bounds__(256, 2) void k_main(const float* __restrict__ x,
        const u16* __restrict__ Qb, const float* __restrict__ csT,
        float* __restrict__ out) {
    __shared__ u16 Plds[128 * 128];      // 32 KB Q (swizzled)
    __shared__ f4 scratch[4][16 * 32];   // 32 KB: per-wave 16 tok x 32 chunks

    // stage Q once (R3 scheme: chunk c of row at c ^ (row&15))
    #pragma unroll
    for (int i = 0; i < 8; ++i) {
        int chunk = i * 256 + threadIdx.x;
        int row = chunk >> 4, c = chunk & 15;
        int pc = c ^ (row & 15);
        bh8 v = *(const bh8*)(Qb + chunk * 8);
        *(bh8*)(&Plds[row * 128 + pc * 8]) = v;
    }
    __syncthreads();

    const int wave = threadIdx.x >> 6;
    const int lane = threadIdx.x & 63;
    const int lhi = (lane >> 4) & 3, llo = lane & 15;
    const int half = lane >> 5;          // 0/1: which of the 2 tokens per inst
    const int c = lane & 31;             // 16B chunk within token row
    f4* scr = scratch[wave];

    const int wbase0 = blockIdx.x * 512 + wave * 16;
    const float sg = (lane & 16) ? 1.0f : -1.0f;   // rotate-half sign

    // preload iter 0's x (store layout: 1KB contiguous per instruction)
    f4 xs[8];
    {
        const float* xb = x + (size_t)wbase0 * E_DIM;
        #pragma unroll
        for (int j = 0; j < 8; ++j)
            xs[j] = *(const f4*)(xb + (2 * j + half) * E_DIM + 4 * c);
    }

    #pragma unroll 1
    for (int it = 0; it < ITERS; ++it) {
        const int wbase = wbase0 + it * 64;

        // [0] cs loads, store layout (1KB contiguous: 2 adjacent csT rows/inst)
        f4 cs[8];
        #pragma unroll
        for (int j = 0; j < 8; ++j) {
            int s = (wbase + 2 * j + half) & (S_LEN - 1);
            cs[j] = *(const f4*)(csT + (size_t)s * 128 + 4 * c);
        }
        __builtin_amdgcn_sched_barrier(0);

        // [1] transpose-in: xs -> scratch (swizzled), read back as frags
        #pragma unroll
        for (int j = 0; j < 8; ++j) {
            int tk = 2 * j + half;
            scr[tk * 32 + (c ^ tk)] = xs[j];
        }
        bh8 frag[4];
        #pragma unroll
        for (int kk = 0; kk < 4; ++kk) {
            int ch0 = kk * 8 + lhi * 2;
            f4 v0 = scr[llo * 32 + (ch0 ^ llo)];
            f4 v1 = scr[llo * 32 + ((ch0 + 1) ^ llo)];
            bh8 a;
            #pragma unroll
            for (int e = 0; e < 4; ++e) { a[e] = bfc(v0[e]); a[4 + e] = bfc(v1[e]); }
            frag[kk] = a;
        }
        __builtin_amdgcn_sched_barrier(0);

        // [2] prefetch next iter's x (issued BEFORE this iter's stores, so
        //     the frag-transpose wait next iter never drains store-acks)
        f4 xsn[8];
        if (it + 1 < ITERS) {
            const float* xb = x + (size_t)(wbase + 64) * E_DIM;
            #pragma unroll
            for (int j = 0; j < 8; ++j)
                xsn[j] = *(const f4*)(xb + (2 * j + half) * E_DIM + 4 * c);
        } else {
            #pragma unroll
            for (int j = 0; j < 8; ++j) xsn[j] = xs[j];
        }
        __builtin_amdgcn_sched_barrier(0);

        // [3] MFMA: acc[t] = (x*Q^T)[token=llo][n=t*16+lhi*4+r]
        f4 acc[8];
        #pragma unroll
        for (int t = 0; t < 8; ++t) { f4 z = {0.f, 0.f, 0.f, 0.f}; acc[t] = z; }
        #pragma unroll
        for (int kk = 0; kk < 4; ++kk) {
            #pragma unroll
            for (int t = 0; t < 8; ++t) {
                int pc = (kk * 4 + lhi) ^ llo;
                bh8 qfrag = *(const bh8*)(&Plds[(t * 16 + llo) * 128 + pc * 8]);
                acc[t] = __builtin_amdgcn_mfma_f32_16x16x32_bf16(qfrag, frag[kk], acc[t], 0, 0, 0);
            }
        }

        // [4] transpose-out: acc (acc layout) -> scratch -> store layout
        #pragma unroll
        for (int t = 0; t < 4; ++t) {
            scr[llo * 32 + ((t * 4 + lhi) ^ llo)]      = acc[t];
            scr[llo * 32 + ((16 + t * 4 + lhi) ^ llo)] = acc[t + 4];
        }
        f4 os[8];
        #pragma unroll
        for (int j = 0; j < 8; ++j) {
            int tk = 2 * j + half;
            os[j] = scr[tk * 32 + (c ^ tk)];
        }

        // [5] epilogue in store layout: xt = os + x; rotate-half via shfl_xor
        float* ob = out + (size_t)wbase * E_DIM;
        #pragma unroll
        for (int j = 0; j < 8; ++j) {
            f4 xt, xp, o;
            #pragma unroll
            for (int e = 0; e < 4; ++e) xt[e] = os[j][e] + xs[j][e];
            #pragma unroll
            for (int e = 0; e < 4; ++e) xp[e] = __shfl_xor(xt[e], 16, 64);
            #pragma unroll
            for (int e = 0; e < 4; ++e) {
                float cv = cs[j][2 * (e >> 1)];
                float sv = cs[j][2 * (e >> 1) + 1];
                o[e] = xt[e] * cv + sg * xp[e] * sv;
            }
            *(f4*)(ob + (2 * j + half) * E_DIM + 4 * c) = o;   // 1KB contiguous
        }

        // rotate pipeline regs
        #pragma unroll
        for (int j = 0; j < 8; ++j) xs[j] = xsn[j];
    }
}

extern "C" void kernel_launch(void* const* d_in, const int* in_sizes, int n_in,
                              void* d_out, int out_size, void* d_ws, size_t ws_size,
                              hipStream_t stream) {
    const float* x   = (const float*)d_in[0];
    const float* pos = (const float*)d_in[1];
    const float* Sc  = (const float*)d_in[2];
    float* out = (float*)d_out;

    char* ws = (char*)d_ws;
    u16* Qb     = (u16*)(ws);              // 32 KB bf16 Q = P - I
    float* csT  = (float*)(ws + 32768);    // 2 MB interleaved cos/sin

    k_pro<<<17, 1024, 0, stream>>>(Sc, pos, Qb, csT);
    k_main<<<GRID_MAIN, 256, 0, stream>>>(x, Qb, csT, out);
}